// Round 1
// baseline (205.222 us; speedup 1.0000x reference)
//
#include <hip/hip_runtime.h>
#include <hip/hip_bf16.h>

// Problem constants (match reference)
#define IN_D 112
#define OUT_D 111
#define MDIM 16

// One thread per output spatial position (d,h,w). Block covers the w axis
// (128 threads, 111 active). grid = (1, 111, 111) -> (w-chunk, h, d).
// M (16x16) staged in LDS; all lanes broadcast-read the same element -> no
// bank conflicts. The /8 window mean is folded into a final *0.125f.
__global__ __launch_bounds__(128)
void spatial_dual_desc_kernel(const float* __restrict__ x,
                              const float* __restrict__ M,
                              float* __restrict__ out) {
    __shared__ float sM[MDIM * MDIM];
    const int tid = threadIdx.x;
    // 128 threads load 256 floats of M
    sM[tid] = M[tid];
    sM[tid + 128] = M[tid + 128];
    __syncthreads();

    const int w = tid;
    const int h = blockIdx.y;
    const int d = blockIdx.z;
    if (w >= OUT_D) return;

    const size_t base = (((size_t)d * IN_D + h) * IN_D + w) * MDIM;

    float s[MDIM];
#pragma unroll
    for (int j = 0; j < MDIM; ++j) s[j] = 0.0f;

    // 2x2x2 window sum; each voxel is 16 contiguous floats = 4 float4 loads
#pragma unroll
    for (int dd = 0; dd < 2; ++dd) {
#pragma unroll
        for (int dh = 0; dh < 2; ++dh) {
#pragma unroll
            for (int dw = 0; dw < 2; ++dw) {
                const float4* v = (const float4*)(x + base +
                    ((size_t)dd * IN_D * IN_D + (size_t)dh * IN_D + dw) * MDIM);
#pragma unroll
                for (int q = 0; q < 4; ++q) {
                    float4 t = v[q];
                    s[q * 4 + 0] += t.x;
                    s[q * 4 + 1] += t.y;
                    s[q * 4 + 2] += t.z;
                    s[q * 4 + 3] += t.w;
                }
            }
        }
    }

    // out[p][i] = (1/8) * sum_j s[j] * M[i][j]
    const size_t p = (((size_t)d * OUT_D + h) * OUT_D + w) * MDIM;
    float4* o = (float4*)(out + p);
#pragma unroll
    for (int i = 0; i < MDIM; i += 4) {
        float a0 = 0.f, a1 = 0.f, a2 = 0.f, a3 = 0.f;
#pragma unroll
        for (int j = 0; j < MDIM; ++j) {
            const float sj = s[j];
            a0 += sj * sM[(i + 0) * MDIM + j];
            a1 += sj * sM[(i + 1) * MDIM + j];
            a2 += sj * sM[(i + 2) * MDIM + j];
            a3 += sj * sM[(i + 3) * MDIM + j];
        }
        float4 r;
        r.x = a0 * 0.125f;
        r.y = a1 * 0.125f;
        r.z = a2 * 0.125f;
        r.w = a3 * 0.125f;
        o[i / 4] = r;
    }
}

extern "C" void kernel_launch(void* const* d_in, const int* in_sizes, int n_in,
                              void* d_out, int out_size, void* d_ws, size_t ws_size,
                              hipStream_t stream) {
    const float* x = (const float*)d_in[0];   // (112,112,112,16) fp32
    const float* M = (const float*)d_in[1];   // (16,16) fp32
    float* out = (float*)d_out;               // (111^3, 16) fp32

    dim3 block(128, 1, 1);
    dim3 grid(1, OUT_D, OUT_D);
    spatial_dual_desc_kernel<<<grid, block, 0, stream>>>(x, M, out);
}

// Round 2
// 186.373 us; speedup vs baseline: 1.1011x; 1.1011x over previous
//
#include <hip/hip_runtime.h>
#include <hip/hip_bf16.h>

#define IN_D 112
#define OUT_D 111
#define MDIM 16

// Block = 128 threads (2 waves) handles one full (d,h) output row (111 outputs).
// Wave k, lane i owns voxel column col = k*63 + i (waves overlap by 1 column so
// the w+1 neighbor never crosses a wave boundary).
// Each lane: 16 independent float4 loads (4 input rows x 4 float4/voxel),
// summed into rowsum[16]. Neighbor column's rowsum via __shfl_down(.,1).
// out = (rowsum + rowsum_next) * 0.125 @ M^T, M broadcast from LDS.
__global__ __launch_bounds__(128)
void spatial_dual_desc_kernel(const float* __restrict__ x,
                              const float* __restrict__ M,
                              float* __restrict__ out) {
    __shared__ float sM[MDIM * MDIM];
    const int tid = threadIdx.x;
    sM[tid] = M[tid];
    sM[tid + 128] = M[tid + 128];
    __syncthreads();

    const int wave = tid >> 6;
    const int lane = tid & 63;
    const int col = wave * 63 + lane;          // 0..126; valid columns are 0..111
    const int h = blockIdx.y;
    const int d = blockIdx.z;

    // Clamp OOB lanes to the last column (their results are masked at store).
    const int c = (col < IN_D) ? col : (IN_D - 1);

    const size_t row_stride  = (size_t)IN_D * MDIM;             // h step
    const size_t slab_stride = (size_t)IN_D * IN_D * MDIM;      // d step
    const float* r00 = x + (((size_t)d * IN_D + h) * IN_D + c) * MDIM;
    const float* r01 = r00 + row_stride;
    const float* r10 = r00 + slab_stride;
    const float* r11 = r10 + row_stride;

    // 16 independent loads — keep them all live so the compiler batches them.
    float4 v[16];
#pragma unroll
    for (int q = 0; q < 4; ++q) v[q]      = ((const float4*)r00)[q];
#pragma unroll
    for (int q = 0; q < 4; ++q) v[4 + q]  = ((const float4*)r01)[q];
#pragma unroll
    for (int q = 0; q < 4; ++q) v[8 + q]  = ((const float4*)r10)[q];
#pragma unroll
    for (int q = 0; q < 4; ++q) v[12 + q] = ((const float4*)r11)[q];

    float rs[MDIM];
#pragma unroll
    for (int q = 0; q < 4; ++q) {
        rs[q * 4 + 0] = v[q].x + v[4 + q].x + v[8 + q].x + v[12 + q].x;
        rs[q * 4 + 1] = v[q].y + v[4 + q].y + v[8 + q].y + v[12 + q].y;
        rs[q * 4 + 2] = v[q].z + v[4 + q].z + v[8 + q].z + v[12 + q].z;
        rs[q * 4 + 3] = v[q].w + v[4 + q].w + v[8 + q].w + v[12 + q].w;
    }

    // Window sum = rowsum[col] + rowsum[col+1] (neighbor lane's value).
    float s[MDIM];
#pragma unroll
    for (int j = 0; j < MDIM; ++j) {
        s[j] = rs[j] + __shfl_down(rs[j], 1, 64);
    }

    const bool emit = (lane < 63) && (col < OUT_D);
    if (emit) {
        const size_t p = (((size_t)d * OUT_D + h) * OUT_D + col) * MDIM;
        float4* o = (float4*)(out + p);
#pragma unroll
        for (int i = 0; i < MDIM; i += 4) {
            float a0 = 0.f, a1 = 0.f, a2 = 0.f, a3 = 0.f;
#pragma unroll
            for (int j = 0; j < MDIM; ++j) {
                const float sj = s[j];
                a0 += sj * sM[(i + 0) * MDIM + j];
                a1 += sj * sM[(i + 1) * MDIM + j];
                a2 += sj * sM[(i + 2) * MDIM + j];
                a3 += sj * sM[(i + 3) * MDIM + j];
            }
            float4 r;
            r.x = a0 * 0.125f;
            r.y = a1 * 0.125f;
            r.z = a2 * 0.125f;
            r.w = a3 * 0.125f;
            o[i / 4] = r;
        }
    }
}

extern "C" void kernel_launch(void* const* d_in, const int* in_sizes, int n_in,
                              void* d_out, int out_size, void* d_ws, size_t ws_size,
                              hipStream_t stream) {
    const float* x = (const float*)d_in[0];   // (112,112,112,16) fp32
    const float* M = (const float*)d_in[1];   // (16,16) fp32
    float* out = (float*)d_out;               // (111^3, 16) fp32

    dim3 block(128, 1, 1);
    dim3 grid(1, OUT_D, OUT_D);
    spatial_dual_desc_kernel<<<grid, block, 0, stream>>>(x, M, out);
}

// Round 3
// 180.495 us; speedup vs baseline: 1.1370x; 1.0326x over previous
//
#include <hip/hip_runtime.h>
#include <hip/hip_bf16.h>

#define IN_D 112
#define OUT_D 111
#define MDIM 16
#define DC 4          // d-outputs per thread (streaming chunk)

// Block = 128 threads (2 waves), owns one h and a chunk of DC outputs along d,
// covering the full w row. Wave k lane i owns column col = k*63 + i (waves
// overlap by one column so the w+1 shfl neighbor never crosses a wave).
// Stream along d: rowsum of slab d is carried in registers; each step loads
// only slab d+1's two rows (h, h+1), double-buffered so the next slab's loads
// are in flight during the current step's matmul+store.
__global__ __launch_bounds__(128)
void spatial_dual_desc_kernel(const float* __restrict__ x,
                              const float* __restrict__ M,
                              float* __restrict__ out) {
    __shared__ float sM[MDIM * MDIM];
    const int tid = threadIdx.x;
    sM[tid] = M[tid];
    sM[tid + 128] = M[tid + 128];
    __syncthreads();

    const int wave = tid >> 6;
    const int lane = tid & 63;
    const int col = wave * 63 + lane;               // 0..126
    const int c = (col < IN_D) ? col : (IN_D - 1);  // clamp OOB lanes
    const int h = blockIdx.y;
    const int d0 = blockIdx.z * DC;

    const size_t row_stride  = (size_t)IN_D * MDIM;
    const size_t slab_stride = (size_t)IN_D * IN_D * MDIM;
    const float* base = x + (((size_t)d0 * IN_D + h) * IN_D + c) * MDIM;

    // --- prologue: slab d0 (rows h, h+1) -> rs_prev ---
    float4 a[8];
#pragma unroll
    for (int q = 0; q < 4; ++q) a[q]     = ((const float4*)base)[q];
#pragma unroll
    for (int q = 0; q < 4; ++q) a[4 + q] = ((const float4*)(base + row_stride))[q];

    float rs_prev[MDIM];
#pragma unroll
    for (int q = 0; q < 4; ++q) {
        rs_prev[q * 4 + 0] = a[q].x + a[4 + q].x;
        rs_prev[q * 4 + 1] = a[q].y + a[4 + q].y;
        rs_prev[q * 4 + 2] = a[q].z + a[4 + q].z;
        rs_prev[q * 4 + 3] = a[q].w + a[4 + q].w;
    }

    // --- prefetch slab d0+1 ---
    float4 b[8];
    {
        const float* p = base + slab_stride;
#pragma unroll
        for (int q = 0; q < 4; ++q) b[q]     = ((const float4*)p)[q];
#pragma unroll
        for (int q = 0; q < 4; ++q) b[4 + q] = ((const float4*)(p + row_stride))[q];
    }

#pragma unroll
    for (int k = 0; k < DC; ++k) {
        const int dcur = d0 + k;

        float rs_new[MDIM];
#pragma unroll
        for (int q = 0; q < 4; ++q) {
            rs_new[q * 4 + 0] = b[q].x + b[4 + q].x;
            rs_new[q * 4 + 1] = b[q].y + b[4 + q].y;
            rs_new[q * 4 + 2] = b[q].z + b[4 + q].z;
            rs_new[q * 4 + 3] = b[q].w + b[4 + q].w;
        }

        // issue next slab's loads NOW (before compute), clamped to last slab
        if (k < DC - 1) {
            const int dn = (d0 + k + 2 < IN_D) ? (d0 + k + 2) : (IN_D - 1);
            const float* p = x + (((size_t)dn * IN_D + h) * IN_D + c) * MDIM;
#pragma unroll
            for (int q = 0; q < 4; ++q) b[q]     = ((const float4*)p)[q];
#pragma unroll
            for (int q = 0; q < 4; ++q) b[4 + q] = ((const float4*)(p + row_stride))[q];
        }

        // window sum across d-pair, then w-pair via shfl
        float s[MDIM];
#pragma unroll
        for (int j = 0; j < MDIM; ++j) {
            const float t = rs_prev[j] + rs_new[j];
            s[j] = t + __shfl_down(t, 1, 64);
        }

        if (lane < 63 && col < OUT_D && dcur < OUT_D) {
            const size_t p = (((size_t)dcur * OUT_D + h) * OUT_D + col) * MDIM;
            float4* o = (float4*)(out + p);
#pragma unroll
            for (int i = 0; i < MDIM; i += 4) {
                float a0 = 0.f, a1 = 0.f, a2 = 0.f, a3 = 0.f;
#pragma unroll
                for (int j = 0; j < MDIM; ++j) {
                    const float sj = s[j];
                    a0 += sj * sM[(i + 0) * MDIM + j];
                    a1 += sj * sM[(i + 1) * MDIM + j];
                    a2 += sj * sM[(i + 2) * MDIM + j];
                    a3 += sj * sM[(i + 3) * MDIM + j];
                }
                float4 r;
                r.x = a0 * 0.125f;
                r.y = a1 * 0.125f;
                r.z = a2 * 0.125f;
                r.w = a3 * 0.125f;
                o[i / 4] = r;
            }
        }

#pragma unroll
        for (int j = 0; j < MDIM; ++j) rs_prev[j] = rs_new[j];
    }
}

extern "C" void kernel_launch(void* const* d_in, const int* in_sizes, int n_in,
                              void* d_out, int out_size, void* d_ws, size_t ws_size,
                              hipStream_t stream) {
    const float* x = (const float*)d_in[0];   // (112,112,112,16) fp32
    const float* M = (const float*)d_in[1];   // (16,16) fp32
    float* out = (float*)d_out;               // (111^3, 16) fp32

    dim3 block(128, 1, 1);
    dim3 grid(1, OUT_D, (OUT_D + DC - 1) / DC);   // 1 x 111 x 28
    spatial_dual_desc_kernel<<<grid, block, 0, stream>>>(x, M, out);
}

// Round 4
// 165.144 us; speedup vs baseline: 1.2427x; 1.0930x over previous
//
#include <hip/hip_runtime.h>
#include <hip/hip_bf16.h>

#define IN_D 112
#define OUT_D 111
#define MDIM 16
#define DC 8   // d-outputs streamed per thread

// Lane layout: lane = 4*ci + q. ci = local column (0..15), q = channel quad
// (0..3, i.e. floats 4q..4q+3). Wave g covers output columns g*15 .. g*15+14
// (16 input columns, 15 outputs; waves overlap by 1 column). All global loads
// and stores are 16 B/lane fully contiguous (1 KB per wave instruction).
// M is held per-lane as a pre-permuted 4x4-of-float4 fragment in VGPRs so the
// quad-exchange matmul uses only compile-time register indices. No LDS.
__device__ __forceinline__ float4 f4add(float4 a, float4 b) {
    return make_float4(a.x + b.x, a.y + b.y, a.z + b.z, a.w + b.w);
}
__device__ __forceinline__ float4 shfl_down4(float4 v) {
    return make_float4(__shfl_down(v.x, 4, 64), __shfl_down(v.y, 4, 64),
                       __shfl_down(v.z, 4, 64), __shfl_down(v.w, 4, 64));
}
__device__ __forceinline__ float4 shfl_xor4(float4 v, int m) {
    return make_float4(__shfl_xor(v.x, m, 64), __shfl_xor(v.y, m, 64),
                       __shfl_xor(v.z, m, 64), __shfl_xor(v.w, m, 64));
}

__global__ __launch_bounds__(256)
void spatial_dual_desc_kernel(const float* __restrict__ x,
                              const float* __restrict__ Mg,
                              float* __restrict__ out) {
    const int lane = threadIdx.x & 63;
    const int wid  = threadIdx.x >> 6;          // 0..3
    const int g    = blockIdx.x * 4 + wid;      // wave slot 0..7
    const int ci   = lane >> 2;                 // 0..15
    const int q    = lane & 3;                  // 0..3
    const int col  = g * 15 + ci;               // candidate output column (0..120)
    const int c    = (col < IN_D) ? col : (IN_D - 1);
    const int h    = blockIdx.y;
    const int d0   = blockIdx.z * DC;

    // Per-lane permuted M fragment: Mreg[i][m] = quad (q^m) of row (4q+i).
    // part m of the window-sum vector arrives from lane^m (which owns quad q^m).
    float4 Mreg[4][4];
#pragma unroll
    for (int i = 0; i < 4; ++i)
#pragma unroll
        for (int m = 0; m < 4; ++m)
            Mreg[i][m] = *(const float4*)(Mg + (4 * q + i) * MDIM + 4 * (q ^ m));

    const size_t row_stride  = (size_t)IN_D * MDIM;          // h step (floats)
    const size_t slab_stride = (size_t)IN_D * row_stride;    // d step (floats)
    const float* bp = x + ((size_t)h * IN_D + c) * MDIM + 4 * q;

    // Prologue: slab d0 row pair -> rs_prev; prefetch slabs d0+1, d0+2.
    float4 a0 = *(const float4*)(bp + (size_t)d0 * slab_stride);
    float4 b0 = *(const float4*)(bp + (size_t)d0 * slab_stride + row_stride);
    float4 buf[2][2];
    buf[0][0] = *(const float4*)(bp + (size_t)(d0 + 1) * slab_stride);
    buf[0][1] = *(const float4*)(bp + (size_t)(d0 + 1) * slab_stride + row_stride);
    buf[1][0] = *(const float4*)(bp + (size_t)(d0 + 2) * slab_stride);
    buf[1][1] = *(const float4*)(bp + (size_t)(d0 + 2) * slab_stride + row_stride);

    float4 rs_prev = f4add(a0, b0);

#pragma unroll
    for (int k = 0; k < DC; ++k) {
        const int dcur = d0 + k;
        float4 ea = buf[k & 1][0];
        float4 eb = buf[k & 1][1];
        float4 rs_new = f4add(ea, eb);   // row-pair sum of slab dcur+1

        // Prefetch slab dcur+3 into the buffer just freed (depth-2 pipeline).
        if (k < DC - 2) {
            int dn = d0 + k + 3;
            if (dn > IN_D - 1) dn = IN_D - 1;
            const float* p = bp + (size_t)dn * slab_stride;
            buf[k & 1][0] = *(const float4*)p;
            buf[k & 1][1] = *(const float4*)(p + row_stride);
        }

        // d-pair, then w-pair (neighbor column = lane+4), per-quad.
        float4 s4 = f4add(rs_prev, rs_new);
        float4 w4 = f4add(s4, shfl_down4(s4));

        // Gather the other 3 quads of the window-sum vector.
        float4 p1 = shfl_xor4(w4, 1);
        float4 p2 = shfl_xor4(w4, 2);
        float4 p3 = shfl_xor4(w4, 3);

        float o[4];
#pragma unroll
        for (int i = 0; i < 4; ++i) {
            float acc;
            acc  = w4.x * Mreg[i][0].x + w4.y * Mreg[i][0].y + w4.z * Mreg[i][0].z + w4.w * Mreg[i][0].w;
            acc += p1.x * Mreg[i][1].x + p1.y * Mreg[i][1].y + p1.z * Mreg[i][1].z + p1.w * Mreg[i][1].w;
            acc += p2.x * Mreg[i][2].x + p2.y * Mreg[i][2].y + p2.z * Mreg[i][2].z + p2.w * Mreg[i][2].w;
            acc += p3.x * Mreg[i][3].x + p3.y * Mreg[i][3].y + p3.z * Mreg[i][3].z + p3.w * Mreg[i][3].w;
            o[i] = acc * 0.125f;
        }

        if (ci < 15 && col < OUT_D && dcur < OUT_D) {
            *(float4*)(out + (((size_t)dcur * OUT_D + h) * OUT_D + col) * MDIM + 4 * q)
                = make_float4(o[0], o[1], o[2], o[3]);
        }
        rs_prev = rs_new;
    }
}

extern "C" void kernel_launch(void* const* d_in, const int* in_sizes, int n_in,
                              void* d_out, int out_size, void* d_ws, size_t ws_size,
                              hipStream_t stream) {
    const float* x = (const float*)d_in[0];   // (112,112,112,16) fp32
    const float* M = (const float*)d_in[1];   // (16,16) fp32
    float* out = (float*)d_out;               // (111^3, 16) fp32

    dim3 block(256, 1, 1);
    dim3 grid(2, OUT_D, (OUT_D + DC - 1) / DC);   // 2 x 111 x 14
    spatial_dual_desc_kernel<<<grid, block, 0, stream>>>(x, M, out);
}

// Round 5
// 162.241 us; speedup vs baseline: 1.2649x; 1.0179x over previous
//
#include <hip/hip_runtime.h>
#include <hip/hip_bf16.h>

#define IN_D 112
#define OUT_D 111
#define MDIM 16
#define DC 8   // d-outputs streamed per thread

// Lane layout: lane = 4*ci + q. ci = local column (0..15), q = channel quad
// (0..3, i.e. floats 4q..4q+3). Wave g covers output columns g*15 .. g*15+14
// (16 input columns, 15 outputs; waves overlap by 1 column). All global loads
// and stores are 16 B/lane fully contiguous (1 KB per wave instruction).
// M is held per-lane as a pre-permuted 4x4-of-float4 fragment in VGPRs.
// __launch_bounds__(256,4): VGPR budget 128 so the 64-float Mreg stays
// RESIDENT (at 64-VGPR budget the compiler re-loaded all 16 M float4s every
// k-step, polluting vmcnt and serializing the stream pipeline — round 4 bug).
__device__ __forceinline__ float4 f4add(float4 a, float4 b) {
    return make_float4(a.x + b.x, a.y + b.y, a.z + b.z, a.w + b.w);
}
__device__ __forceinline__ float4 shfl_down4(float4 v) {
    return make_float4(__shfl_down(v.x, 4, 64), __shfl_down(v.y, 4, 64),
                       __shfl_down(v.z, 4, 64), __shfl_down(v.w, 4, 64));
}
__device__ __forceinline__ float4 shfl_xor4(float4 v, int m) {
    return make_float4(__shfl_xor(v.x, m, 64), __shfl_xor(v.y, m, 64),
                       __shfl_xor(v.z, m, 64), __shfl_xor(v.w, m, 64));
}

__global__ __launch_bounds__(256, 4)
void spatial_dual_desc_kernel(const float* __restrict__ x,
                              const float* __restrict__ Mg,
                              float* __restrict__ out) {
    const int lane = threadIdx.x & 63;
    const int wid  = threadIdx.x >> 6;          // 0..3
    const int g    = blockIdx.x * 4 + wid;      // wave slot 0..7
    const int ci   = lane >> 2;                 // 0..15
    const int q    = lane & 3;                  // 0..3
    const int col  = g * 15 + ci;               // candidate output column (0..120)
    const int c    = (col < IN_D) ? col : (IN_D - 1);
    const int h    = blockIdx.y;
    const int d0   = blockIdx.z * DC;

    // Per-lane permuted M fragment: Mreg[i][m] = quad (q^m) of row (4q+i).
    // part m of the window-sum vector arrives from lane^m (which owns quad q^m).
    float4 Mreg[4][4];
#pragma unroll
    for (int i = 0; i < 4; ++i)
#pragma unroll
        for (int m = 0; m < 4; ++m)
            Mreg[i][m] = *(const float4*)(Mg + (4 * q + i) * MDIM + 4 * (q ^ m));

    const size_t row_stride  = (size_t)IN_D * MDIM;          // h step (floats)
    const size_t slab_stride = (size_t)IN_D * row_stride;    // d step (floats)
    const float* bp = x + ((size_t)h * IN_D + c) * MDIM + 4 * q;

    // Prologue: slab d0 row pair -> rs_prev; prefetch slabs d0+1, d0+2.
    float4 a0 = *(const float4*)(bp + (size_t)d0 * slab_stride);
    float4 b0 = *(const float4*)(bp + (size_t)d0 * slab_stride + row_stride);
    float4 buf[2][2];
    buf[0][0] = *(const float4*)(bp + (size_t)(d0 + 1) * slab_stride);
    buf[0][1] = *(const float4*)(bp + (size_t)(d0 + 1) * slab_stride + row_stride);
    buf[1][0] = *(const float4*)(bp + (size_t)(d0 + 2) * slab_stride);
    buf[1][1] = *(const float4*)(bp + (size_t)(d0 + 2) * slab_stride + row_stride);

    float4 rs_prev = f4add(a0, b0);

#pragma unroll
    for (int k = 0; k < DC; ++k) {
        const int dcur = d0 + k;
        float4 ea = buf[k & 1][0];
        float4 eb = buf[k & 1][1];
        float4 rs_new = f4add(ea, eb);   // row-pair sum of slab dcur+1

        // Prefetch slab dcur+3 into the buffer just freed (depth-2 pipeline).
        if (k < DC - 2) {
            int dn = d0 + k + 3;
            if (dn > IN_D - 1) dn = IN_D - 1;
            const float* p = bp + (size_t)dn * slab_stride;
            buf[k & 1][0] = *(const float4*)p;
            buf[k & 1][1] = *(const float4*)(p + row_stride);
        }

        // d-pair, then w-pair (neighbor column = lane+4), per-quad.
        float4 s4 = f4add(rs_prev, rs_new);
        float4 w4 = f4add(s4, shfl_down4(s4));

        // Gather the other 3 quads of the window-sum vector.
        float4 p1 = shfl_xor4(w4, 1);
        float4 p2 = shfl_xor4(w4, 2);
        float4 p3 = shfl_xor4(w4, 3);

        float o[4];
#pragma unroll
        for (int i = 0; i < 4; ++i) {
            float acc;
            acc  = w4.x * Mreg[i][0].x + w4.y * Mreg[i][0].y + w4.z * Mreg[i][0].z + w4.w * Mreg[i][0].w;
            acc += p1.x * Mreg[i][1].x + p1.y * Mreg[i][1].y + p1.z * Mreg[i][1].z + p1.w * Mreg[i][1].w;
            acc += p2.x * Mreg[i][2].x + p2.y * Mreg[i][2].y + p2.z * Mreg[i][2].z + p2.w * Mreg[i][2].w;
            acc += p3.x * Mreg[i][3].x + p3.y * Mreg[i][3].y + p3.z * Mreg[i][3].z + p3.w * Mreg[i][3].w;
            o[i] = acc * 0.125f;
        }

        if (ci < 15 && col < OUT_D && dcur < OUT_D) {
            *(float4*)(out + (((size_t)dcur * OUT_D + h) * OUT_D + col) * MDIM + 4 * q)
                = make_float4(o[0], o[1], o[2], o[3]);
        }
        rs_prev = rs_new;
    }
}

extern "C" void kernel_launch(void* const* d_in, const int* in_sizes, int n_in,
                              void* d_out, int out_size, void* d_ws, size_t ws_size,
                              hipStream_t stream) {
    const float* x = (const float*)d_in[0];   // (112,112,112,16) fp32
    const float* M = (const float*)d_in[1];   // (16,16) fp32
    float* out = (float*)d_out;               // (111^3, 16) fp32

    dim3 block(256, 1, 1);
    dim3 grid(2, OUT_D, (OUT_D + DC - 1) / DC);   // 2 x 111 x 14
    spatial_dual_desc_kernel<<<grid, block, 0, stream>>>(x, M, out);
}